// Round 4
// baseline (321.700 us; speedup 1.0000x reference)
//
#include <hip/hip_runtime.h>
#include <math.h>

// Problem constants
#define NN 512
#define DD 512
#define NPAIRS 130816            // 512*511/2
#define TYPES_OFF 0              // [P,10] floats
#define ARGMAX_OFF 1308160      // [P] floats
#define STRENGTH_OFF 1438976    // [P] floats

// ws layout (byte offsets):
//   ca_d  double[512][512]  @ 0          (cb1 + features@cw1[:D], fp64)
//   cb_d  double[512][512]  @ 2097152    (features@cw1[D:],       fp64)
//   sa_f  float [512][256]  @ 4194304    (sb1 + features@sw1[:D], fp32)
//   sb_f  float [512][256]  @ 4718592    (features@sw1[D:],       fp32)
//   cw2d  double[512][10]   @ 5242880
// total 5,283,840 bytes

// init: ca_d rows = cb1 (bias folded), cb_d = 0; sa_f rows = sb1, sb_f = 0; cw2 -> fp64.
__global__ __launch_bounds__(256) void init_ws_kernel(
    const float* __restrict__ cb1, const float* __restrict__ sb1,
    const float* __restrict__ cw2,
    double* __restrict__ ca_d, double* __restrict__ cb_d,
    float* __restrict__ sa_f, float* __restrict__ sb_f,
    double* __restrict__ cw2d)
{
    int idx = blockIdx.x * 256 + threadIdx.x;      // grid 1024 -> 262144
    ca_d[idx] = (double)cb1[idx & 511];
    cb_d[idx] = 0.0;
    if (idx < 131072) {
        sa_f[idx] = sb1[idx & 255];
        sb_f[idx] = 0.f;
    }
    if (idx < 5120) cw2d[idx] = (double)cw2[idx];
}

// Fused projections. Blocks [0,512):   fp64 classifier proj, 64x64 tile, K-split 4 (K=128).
//                   Blocks [512,640): fp32 strength proj,   64x64 tile, K-split 2 (K=256).
// BK=32, 4x4 micro-tile per thread; partials combined with unsafeAtomicAdd.
__global__ __launch_bounds__(256, 4) void proj_kernel(
    const float* __restrict__ F, const float* __restrict__ cw1,
    const float* __restrict__ sw1,
    double* __restrict__ ca_d, double* __restrict__ cb_d,
    float* __restrict__ sa_f, float* __restrict__ sb_f)
{
    __shared__ double sh[2 * 32 * 66];   // 33792 B; fp32 branch overlays (needs 17408 B)

    const int t = threadIdx.x;
    const int b = blockIdx.x;

    // staging indices
    const int arow = t & 63, aq = t >> 6;   // A: row 0..63, k-quad 0..3 (handles aq, aq+4)
    const int bkr = t >> 4, bnq = t & 15;   // B: k-row 0..15 (handles bkr, bkr+16), col-quad
    // compute indices
    const int ty = t >> 4, tx = t & 15;     // 4-row group, 4-col group

    if (b < 512) {
        // ---------------- fp64 classifier projection ----------------
        const int z  = b >> 7;           // K quarter: [z*128, z*128+128)
        const int r  = b & 127;
        const int m0 = (r >> 4) * 64;
        const int ng = (r & 15) * 64;    // 0..960 over 1024 cols
        const float* Bp  = (ng < 512) ? cw1 : cw1 + 512 * 512;
        double* outp     = (ng < 512) ? ca_d : cb_d;
        const int coloff = (ng < 512) ? ng : ng - 512;

        double* As = sh;                 // [32][66], [k][m]
        double* Bs = sh + 32 * 66;       // [32][66], [k][n]

        double acc[4][4];
        #pragma unroll
        for (int r2 = 0; r2 < 4; ++r2)
            #pragma unroll
            for (int c2 = 0; c2 < 4; ++c2) acc[r2][c2] = 0.0;

        for (int k0 = z * 128; k0 < z * 128 + 128; k0 += 32) {
            float4 fa0 = *(const float4*)&F [(m0 + arow) * 512 + k0 + aq * 4];
            float4 fa1 = *(const float4*)&F [(m0 + arow) * 512 + k0 + (aq + 4) * 4];
            float4 fb0 = *(const float4*)&Bp[(k0 + bkr) * 512 + coloff + bnq * 4];
            float4 fb1 = *(const float4*)&Bp[(k0 + bkr + 16) * 512 + coloff + bnq * 4];
            __syncthreads();
            As[(aq * 4 + 0) * 66 + arow] = (double)fa0.x;
            As[(aq * 4 + 1) * 66 + arow] = (double)fa0.y;
            As[(aq * 4 + 2) * 66 + arow] = (double)fa0.z;
            As[(aq * 4 + 3) * 66 + arow] = (double)fa0.w;
            As[((aq + 4) * 4 + 0) * 66 + arow] = (double)fa1.x;
            As[((aq + 4) * 4 + 1) * 66 + arow] = (double)fa1.y;
            As[((aq + 4) * 4 + 2) * 66 + arow] = (double)fa1.z;
            As[((aq + 4) * 4 + 3) * 66 + arow] = (double)fa1.w;
            {
                double2* bd = (double2*)&Bs[bkr * 66 + bnq * 4];
                bd[0] = make_double2((double)fb0.x, (double)fb0.y);
                bd[1] = make_double2((double)fb0.z, (double)fb0.w);
                double2* bd2 = (double2*)&Bs[(bkr + 16) * 66 + bnq * 4];
                bd2[0] = make_double2((double)fb1.x, (double)fb1.y);
                bd2[1] = make_double2((double)fb1.z, (double)fb1.w);
            }
            __syncthreads();
            #pragma unroll
            for (int kk = 0; kk < 32; ++kk) {
                double2 a0 = *(double2*)&As[kk * 66 + ty * 4];
                double2 a1 = *(double2*)&As[kk * 66 + ty * 4 + 2];
                double2 b0 = *(double2*)&Bs[kk * 66 + tx * 4];
                double2 b1 = *(double2*)&Bs[kk * 66 + tx * 4 + 2];
                double av[4] = {a0.x, a0.y, a1.x, a1.y};
                double bv[4] = {b0.x, b0.y, b1.x, b1.y};
                #pragma unroll
                for (int r2 = 0; r2 < 4; ++r2)
                    #pragma unroll
                    for (int c2 = 0; c2 < 4; ++c2)
                        acc[r2][c2] = fma(av[r2], bv[c2], acc[r2][c2]);
            }
        }
        #pragma unroll
        for (int r2 = 0; r2 < 4; ++r2)
            #pragma unroll
            for (int c2 = 0; c2 < 4; ++c2)
                unsafeAtomicAdd(&outp[(m0 + ty * 4 + r2) * 512 + coloff + tx * 4 + c2],
                                acc[r2][c2]);
    } else {
        // ---------------- fp32 strength projection ----------------
        const int b2 = b - 512;
        const int z  = b2 >> 6;          // K half: [z*256, z*256+256)
        const int r  = b2 & 63;
        const int m0 = (r >> 3) * 64;
        const int ng = (r & 7) * 64;     // 0..448 over 512 cols
        const float* Bp  = (ng < 256) ? sw1 : sw1 + 512 * 256;
        float* outp      = (ng < 256) ? sa_f : sb_f;
        const int coloff = (ng < 256) ? ng : ng - 256;

        float* Asf = (float*)sh;         // [32][68]
        float* Bsf = (float*)sh + 32 * 68;

        float acc[4][4];
        #pragma unroll
        for (int r2 = 0; r2 < 4; ++r2)
            #pragma unroll
            for (int c2 = 0; c2 < 4; ++c2) acc[r2][c2] = 0.f;

        for (int k0 = z * 256; k0 < z * 256 + 256; k0 += 32) {
            float4 fa0 = *(const float4*)&F [(m0 + arow) * 512 + k0 + aq * 4];
            float4 fa1 = *(const float4*)&F [(m0 + arow) * 512 + k0 + (aq + 4) * 4];
            float4 fb0 = *(const float4*)&Bp[(k0 + bkr) * 256 + coloff + bnq * 4];
            float4 fb1 = *(const float4*)&Bp[(k0 + bkr + 16) * 256 + coloff + bnq * 4];
            __syncthreads();
            Asf[(aq * 4 + 0) * 68 + arow] = fa0.x;
            Asf[(aq * 4 + 1) * 68 + arow] = fa0.y;
            Asf[(aq * 4 + 2) * 68 + arow] = fa0.z;
            Asf[(aq * 4 + 3) * 68 + arow] = fa0.w;
            Asf[((aq + 4) * 4 + 0) * 68 + arow] = fa1.x;
            Asf[((aq + 4) * 4 + 1) * 68 + arow] = fa1.y;
            Asf[((aq + 4) * 4 + 2) * 68 + arow] = fa1.z;
            Asf[((aq + 4) * 4 + 3) * 68 + arow] = fa1.w;
            *(float4*)&Bsf[bkr * 68 + bnq * 4] = fb0;
            *(float4*)&Bsf[(bkr + 16) * 68 + bnq * 4] = fb1;
            __syncthreads();
            #pragma unroll
            for (int kk = 0; kk < 32; ++kk) {
                float4 a4 = *(float4*)&Asf[kk * 68 + ty * 4];
                float4 b4 = *(float4*)&Bsf[kk * 68 + tx * 4];
                float av[4] = {a4.x, a4.y, a4.z, a4.w};
                float bv[4] = {b4.x, b4.y, b4.z, b4.w};
                #pragma unroll
                for (int r2 = 0; r2 < 4; ++r2)
                    #pragma unroll
                    for (int c2 = 0; c2 < 4; ++c2)
                        acc[r2][c2] = fmaf(av[r2], bv[c2], acc[r2][c2]);
            }
        }
        #pragma unroll
        for (int r2 = 0; r2 < 4; ++r2)
            #pragma unroll
            for (int c2 = 0; c2 < 4; ++c2)
                unsafeAtomicAdd(&outp[(m0 + ty * 4 + r2) * 256 + coloff + tx * 4 + c2],
                                acc[r2][c2]);
    }
}

// Pair phase: block = 8x8 pair tile, 4 waves = 4 K-quarters, LDS combine.
// Grid: 2080 triangular tiles (64x64 tile space, bj >= bi).
__global__ __launch_bounds__(256, 4) void pair_kernel(
    const double* __restrict__ ca_d, const double* __restrict__ cb_d,
    const float* __restrict__ sa_f, const float* __restrict__ sb_f,
    const double* __restrict__ cw2d, const float* __restrict__ cb2,
    const float* __restrict__ sw2, const float* __restrict__ sb2,
    float* __restrict__ out)
{
    // triangular tile decode: S(bi) = bi*(129-bi)/2
    const int b = blockIdx.x;
    int bi = (int)floorf((129.0f - sqrtf(16641.0f - 8.0f * (float)b)) * 0.5f);
    while ((bi + 1) * (129 - (bi + 1)) / 2 <= b) ++bi;
    while (bi * (129 - bi) / 2 > b) --bi;
    const int bj = bi + (b - bi * (129 - bi) / 2);
    const int i0 = bi * 8, j0 = bj * 8;

    const int t = threadIdx.x;
    const int q  = t >> 6;                               // K-quarter = wave id
    const int qu = __builtin_amdgcn_readfirstlane(q);    // wave-uniform -> s_load bases
    const int l = t & 63;
    const int pi = l >> 3, pj = l & 7;
    const int i = i0 + pi, j = j0 + pj;

    __shared__ double smem_d[2176];                 // 17408 B
    double* sA  = smem_d;                           // [4*8][34]
    double* sB  = smem_d + 1088;
    float*  sSa = (float*)smem_d;                   // [4*8][68]
    float*  sSb = (float*)smem_d + 2176;
    double* lgbuf = smem_d;                         // [3][64][10]
    float*  stbuf = (float*)(smem_d + 1920);        // [3][64]

    // ---------------- strength (fp32), K=64 per quarter ----------------
    #pragma unroll
    for (int u = 0; u < 4; ++u) {
        int idx = u * 256 + t;
        int kq  = idx & 15;
        int row = (idx >> 4) & 7;
        int qq  = (idx >> 7) & 3;
        int arr = idx >> 9;
        const float* src = arr ? (sb_f + (j0 + row) * 256) : (sa_f + (i0 + row) * 256);
        float4 v = *(const float4*)(src + qq * 64 + kq * 4);
        float* dst = (arr ? sSb : sSa) + (qq * 8 + row) * 68 + kq * 4;
        *(float4*)dst = v;
    }
    __syncthreads();
    float accs = 0.f;
    {
        const float* sw2q = sw2 + qu * 64;
        const float* ra = sSa + (q * 8 + pi) * 68;
        const float* rb = sSb + (q * 8 + pj) * 68;
        #pragma unroll
        for (int kk = 0; kk < 64; kk += 4) {
            float4 a4 = *(const float4*)&ra[kk];
            float4 b4 = *(const float4*)&rb[kk];
            accs = fmaf(fmaxf(a4.x + b4.x, 0.f), sw2q[kk + 0], accs);
            accs = fmaf(fmaxf(a4.y + b4.y, 0.f), sw2q[kk + 1], accs);
            accs = fmaf(fmaxf(a4.z + b4.z, 0.f), sw2q[kk + 2], accs);
            accs = fmaf(fmaxf(a4.w + b4.w, 0.f), sw2q[kk + 3], accs);
        }
    }

    // ---------------- classifier (fp64), K=128 per quarter ----------------
    double lg[10];
    #pragma unroll
    for (int c = 0; c < 10; ++c) lg[c] = 0.0;
    const double* wq = cw2d + qu * 1280;

    for (int c4 = 0; c4 < 4; ++c4) {
        __syncthreads();   // prior reads of sA/sB (or sSa/sSb) done
        #pragma unroll
        for (int u = 0; u < 4; ++u) {
            int idx = u * 256 + t;
            int kq  = idx & 15;
            int row = (idx >> 4) & 7;
            int qq  = (idx >> 7) & 3;
            int arr = idx >> 9;
            const double* src = arr ? (cb_d + (j0 + row) * 512) : (ca_d + (i0 + row) * 512);
            double2 v = *(const double2*)(src + qq * 128 + c4 * 32 + kq * 2);
            double* dst = (arr ? sB : sA) + (qq * 8 + row) * 34 + kq * 2;
            *(double2*)dst = v;
        }
        __syncthreads();
        const double* ra = sA + (q * 8 + pi) * 34;
        const double* rb = sB + (q * 8 + pj) * 34;
        const double* wc = wq + c4 * 320;
        #pragma unroll
        for (int kk = 0; kk < 32; kk += 2) {
            double2 a2 = *(const double2*)&ra[kk];
            double2 b2 = *(const double2*)&rb[kk];
            double h0 = fmax(a2.x + b2.x, 0.0);
            double h1 = fmax(a2.y + b2.y, 0.0);
            const double* w0 = wc + kk * 10;
            #pragma unroll
            for (int c = 0; c < 10; ++c) lg[c] = fma(h0, w0[c], lg[c]);
            #pragma unroll
            for (int c = 0; c < 10; ++c) lg[c] = fma(h1, w0[10 + c], lg[c]);
        }
    }

    // ---------------- combine via LDS ----------------
    __syncthreads();
    if (q > 0) {
        double* dst = lgbuf + ((q - 1) * 64 + l) * 10;
        #pragma unroll
        for (int c = 0; c < 10; ++c) dst[c] = lg[c];
        stbuf[(q - 1) * 64 + l] = accs;
    }
    __syncthreads();
    if (q == 0) {
        #pragma unroll
        for (int w = 0; w < 3; ++w) {
            const double* srcb = lgbuf + (w * 64 + l) * 10;
            #pragma unroll
            for (int c = 0; c < 10; ++c) lg[c] += srcb[c];
        }
        float st = accs + stbuf[l] + stbuf[64 + l] + stbuf[128 + l] + sb2[0];

        #pragma unroll
        for (int c = 0; c < 10; ++c) lg[c] += (double)cb2[c];
        double mx = lg[0]; int am2 = 0;
        #pragma unroll
        for (int c = 1; c < 10; ++c) {
            if (lg[c] > mx) { mx = lg[c]; am2 = c; }   // first-max == np.argmax
        }
        float tf[10]; float s = 0.f;
        #pragma unroll
        for (int c = 0; c < 10; ++c) { tf[c] = (float)(lg[c] - mx); s += __expf(tf[c]); }
        float ls = __logf(s);

        if (j > i) {
            const int p = i * 511 - (i * (i - 1)) / 2 + (j - i - 1);
            float* tp = out + TYPES_OFF + p * 10;
            #pragma unroll
            for (int c = 0; c < 10; ++c) tp[c] = tf[c] - ls;
            out[ARGMAX_OFF + p] = (float)am2;
            out[STRENGTH_OFF + p] = 1.0f / (1.0f + __expf(-st));
        }
    }
}

extern "C" void kernel_launch(void* const* d_in, const int* in_sizes, int n_in,
                              void* d_out, int out_size, void* d_ws, size_t ws_size,
                              hipStream_t stream) {
    const float* F   = (const float*)d_in[0];
    const float* cw1 = (const float*)d_in[1];
    const float* cb1 = (const float*)d_in[2];
    const float* cw2 = (const float*)d_in[3];
    const float* cb2 = (const float*)d_in[4];
    const float* sw1 = (const float*)d_in[5];
    const float* sb1 = (const float*)d_in[6];
    const float* sw2 = (const float*)d_in[7];
    const float* sb2 = (const float*)d_in[8];
    float* out = (float*)d_out;

    char* ws = (char*)d_ws;
    double* ca_d = (double*)(ws);
    double* cb_d = (double*)(ws + 2097152);
    float*  sa_f = (float*)(ws + 4194304);
    float*  sb_f = (float*)(ws + 4718592);
    double* cw2d = (double*)(ws + 5242880);

    hipLaunchKernelGGL(init_ws_kernel, dim3(1024), dim3(256), 0, stream,
                       cb1, sb1, cw2, ca_d, cb_d, sa_f, sb_f, cw2d);
    hipLaunchKernelGGL(proj_kernel, dim3(640), dim3(256), 0, stream,
                       F, cw1, sw1, ca_d, cb_d, sa_f, sb_f);
    hipLaunchKernelGGL(pair_kernel, dim3(2080), dim3(256), 0, stream,
                       ca_d, cb_d, sa_f, sb_f, cw2d, cb2, sw2, sb2, out);
}

// Round 5
// 184.842 us; speedup vs baseline: 1.7404x; 1.7404x over previous
//
#include <hip/hip_runtime.h>
#include <math.h>

// Problem constants
#define NN 512
#define DD 512
#define NPAIRS 130816            // 512*511/2
#define TYPES_OFF 0              // [P,10] floats
#define ARGMAX_OFF 1308160      // [P] floats
#define STRENGTH_OFF 1438976    // [P] floats

// ws layout (byte offsets):
//   ca_d  double[512][512]  @ 0          (cb1 + features@cw1[:D], fp64)
//   cb_d  double[512][512]  @ 2097152    (features@cw1[D:],       fp64)
//   sa_f  float [512][256]  @ 4194304    (sb1 + features@sw1[:D], fp32)
//   sb_f  float [512][256]  @ 4718592    (features@sw1[D:],       fp32)
//   cw2d  double[512][10]   @ 5242880
// total 5,283,840 bytes

// init: ca_d rows = cb1 (bias folded), cb_d = 0; sa_f rows = sb1, sb_f = 0; cw2 -> fp64.
__global__ __launch_bounds__(256) void init_ws_kernel(
    const float* __restrict__ cb1, const float* __restrict__ sb1,
    const float* __restrict__ cw2,
    double* __restrict__ ca_d, double* __restrict__ cb_d,
    float* __restrict__ sa_f, float* __restrict__ sb_f,
    double* __restrict__ cw2d)
{
    int idx = blockIdx.x * 256 + threadIdx.x;      // grid 1024 -> 262144
    ca_d[idx] = (double)cb1[idx & 511];
    cb_d[idx] = 0.0;
    if (idx < 131072) {
        sa_f[idx] = sb1[idx & 255];
        sb_f[idx] = 0.f;
    }
    if (idx < 5120) cw2d[idx] = (double)cw2[idx];
}

// Fused projections. Blocks [0,512):   fp64 classifier proj, 64x64 tile, K-split 4 (K=128).
//                   Blocks [512,640): fp32 strength proj,   64x64 tile, K-split 2 (K=256).
// BK=32, 4x4 micro-tile per thread; partials combined with unsafeAtomicAdd.
__global__ __launch_bounds__(256, 4) void proj_kernel(
    const float* __restrict__ F, const float* __restrict__ cw1,
    const float* __restrict__ sw1,
    double* __restrict__ ca_d, double* __restrict__ cb_d,
    float* __restrict__ sa_f, float* __restrict__ sb_f)
{
    __shared__ double sh[2 * 32 * 66];   // 33792 B; fp32 branch overlays (needs 17408 B)

    const int t = threadIdx.x;
    const int b = blockIdx.x;

    // staging indices
    const int arow = t & 63, aq = t >> 6;   // A: row 0..63, k-quad 0..3 (handles aq, aq+4)
    const int bkr = t >> 4, bnq = t & 15;   // B: k-row 0..15 (handles bkr, bkr+16), col-quad
    // compute indices
    const int ty = t >> 4, tx = t & 15;     // 4-row group, 4-col group

    if (b < 512) {
        // ---------------- fp64 classifier projection ----------------
        const int z  = b >> 7;           // K quarter: [z*128, z*128+128)
        const int r  = b & 127;
        const int m0 = (r >> 4) * 64;
        const int ng = (r & 15) * 64;    // 0..960 over 1024 cols
        const float* Bp  = (ng < 512) ? cw1 : cw1 + 512 * 512;
        double* outp     = (ng < 512) ? ca_d : cb_d;
        const int coloff = (ng < 512) ? ng : ng - 512;

        double* As = sh;                 // [32][66], [k][m]
        double* Bs = sh + 32 * 66;       // [32][66], [k][n]

        double acc[4][4];
        #pragma unroll
        for (int r2 = 0; r2 < 4; ++r2)
            #pragma unroll
            for (int c2 = 0; c2 < 4; ++c2) acc[r2][c2] = 0.0;

        for (int k0 = z * 128; k0 < z * 128 + 128; k0 += 32) {
            float4 fa0 = *(const float4*)&F [(m0 + arow) * 512 + k0 + aq * 4];
            float4 fa1 = *(const float4*)&F [(m0 + arow) * 512 + k0 + (aq + 4) * 4];
            float4 fb0 = *(const float4*)&Bp[(k0 + bkr) * 512 + coloff + bnq * 4];
            float4 fb1 = *(const float4*)&Bp[(k0 + bkr + 16) * 512 + coloff + bnq * 4];
            __syncthreads();
            As[(aq * 4 + 0) * 66 + arow] = (double)fa0.x;
            As[(aq * 4 + 1) * 66 + arow] = (double)fa0.y;
            As[(aq * 4 + 2) * 66 + arow] = (double)fa0.z;
            As[(aq * 4 + 3) * 66 + arow] = (double)fa0.w;
            As[((aq + 4) * 4 + 0) * 66 + arow] = (double)fa1.x;
            As[((aq + 4) * 4 + 1) * 66 + arow] = (double)fa1.y;
            As[((aq + 4) * 4 + 2) * 66 + arow] = (double)fa1.z;
            As[((aq + 4) * 4 + 3) * 66 + arow] = (double)fa1.w;
            {
                double2* bd = (double2*)&Bs[bkr * 66 + bnq * 4];
                bd[0] = make_double2((double)fb0.x, (double)fb0.y);
                bd[1] = make_double2((double)fb0.z, (double)fb0.w);
                double2* bd2 = (double2*)&Bs[(bkr + 16) * 66 + bnq * 4];
                bd2[0] = make_double2((double)fb1.x, (double)fb1.y);
                bd2[1] = make_double2((double)fb1.z, (double)fb1.w);
            }
            __syncthreads();
            #pragma unroll
            for (int kk = 0; kk < 32; ++kk) {
                double2 a0 = *(double2*)&As[kk * 66 + ty * 4];
                double2 a1 = *(double2*)&As[kk * 66 + ty * 4 + 2];
                double2 b0 = *(double2*)&Bs[kk * 66 + tx * 4];
                double2 b1 = *(double2*)&Bs[kk * 66 + tx * 4 + 2];
                double av[4] = {a0.x, a0.y, a1.x, a1.y};
                double bv[4] = {b0.x, b0.y, b1.x, b1.y};
                #pragma unroll
                for (int r2 = 0; r2 < 4; ++r2)
                    #pragma unroll
                    for (int c2 = 0; c2 < 4; ++c2)
                        acc[r2][c2] = fma(av[r2], bv[c2], acc[r2][c2]);
            }
        }
        #pragma unroll
        for (int r2 = 0; r2 < 4; ++r2)
            #pragma unroll
            for (int c2 = 0; c2 < 4; ++c2)
                unsafeAtomicAdd(&outp[(m0 + ty * 4 + r2) * 512 + coloff + tx * 4 + c2],
                                acc[r2][c2]);
    } else {
        // ---------------- fp32 strength projection ----------------
        const int b2 = b - 512;
        const int z  = b2 >> 6;          // K half: [z*256, z*256+256)
        const int r  = b2 & 63;
        const int m0 = (r >> 3) * 64;
        const int ng = (r & 7) * 64;     // 0..448 over 512 cols
        const float* Bp  = (ng < 256) ? sw1 : sw1 + 512 * 256;
        float* outp      = (ng < 256) ? sa_f : sb_f;
        const int coloff = (ng < 256) ? ng : ng - 256;

        float* Asf = (float*)sh;         // [32][68]
        float* Bsf = (float*)sh + 32 * 68;

        float acc[4][4];
        #pragma unroll
        for (int r2 = 0; r2 < 4; ++r2)
            #pragma unroll
            for (int c2 = 0; c2 < 4; ++c2) acc[r2][c2] = 0.f;

        for (int k0 = z * 256; k0 < z * 256 + 256; k0 += 32) {
            float4 fa0 = *(const float4*)&F [(m0 + arow) * 512 + k0 + aq * 4];
            float4 fa1 = *(const float4*)&F [(m0 + arow) * 512 + k0 + (aq + 4) * 4];
            float4 fb0 = *(const float4*)&Bp[(k0 + bkr) * 256 + coloff + bnq * 4];
            float4 fb1 = *(const float4*)&Bp[(k0 + bkr + 16) * 256 + coloff + bnq * 4];
            __syncthreads();
            Asf[(aq * 4 + 0) * 68 + arow] = fa0.x;
            Asf[(aq * 4 + 1) * 68 + arow] = fa0.y;
            Asf[(aq * 4 + 2) * 68 + arow] = fa0.z;
            Asf[(aq * 4 + 3) * 68 + arow] = fa0.w;
            Asf[((aq + 4) * 4 + 0) * 68 + arow] = fa1.x;
            Asf[((aq + 4) * 4 + 1) * 68 + arow] = fa1.y;
            Asf[((aq + 4) * 4 + 2) * 68 + arow] = fa1.z;
            Asf[((aq + 4) * 4 + 3) * 68 + arow] = fa1.w;
            *(float4*)&Bsf[bkr * 68 + bnq * 4] = fb0;
            *(float4*)&Bsf[(bkr + 16) * 68 + bnq * 4] = fb1;
            __syncthreads();
            #pragma unroll
            for (int kk = 0; kk < 32; ++kk) {
                float4 a4 = *(float4*)&Asf[kk * 68 + ty * 4];
                float4 b4 = *(float4*)&Bsf[kk * 68 + tx * 4];
                float av[4] = {a4.x, a4.y, a4.z, a4.w};
                float bv[4] = {b4.x, b4.y, b4.z, b4.w};
                #pragma unroll
                for (int r2 = 0; r2 < 4; ++r2)
                    #pragma unroll
                    for (int c2 = 0; c2 < 4; ++c2)
                        acc[r2][c2] = fmaf(av[r2], bv[c2], acc[r2][c2]);
            }
        }
        #pragma unroll
        for (int r2 = 0; r2 < 4; ++r2)
            #pragma unroll
            for (int c2 = 0; c2 < 4; ++c2)
                unsafeAtomicAdd(&outp[(m0 + ty * 4 + r2) * 256 + coloff + tx * 4 + c2],
                                acc[r2][c2]);
    }
}

// Pair phase: block = 8x8 pair tile, 4 waves = 4 K-quarters, LDS combine.
// Grid: 2080 triangular tiles (64x64 tile space, bj >= bi).
// NOTE: inner loops MUST stay scalar-read + partial-unroll (R3 form). Full unroll
// or wider per-iter weight footprints make the compiler hoist weight rows ->
// VGPR pressure explosion -> lg[] spills to scratch (R2: 175 MB, R4: 149 MB
// WRITE_SIZE). Keep weights loaded just-in-time, 10 at a time.
__global__ __launch_bounds__(256, 4) void pair_kernel(
    const double* __restrict__ ca_d, const double* __restrict__ cb_d,
    const float* __restrict__ sa_f, const float* __restrict__ sb_f,
    const double* __restrict__ cw2d, const float* __restrict__ cb2,
    const float* __restrict__ sw2, const float* __restrict__ sb2,
    float* __restrict__ out)
{
    // triangular tile decode: S(bi) = bi*(129-bi)/2
    const int b = blockIdx.x;
    int bi = (int)floorf((129.0f - sqrtf(16641.0f - 8.0f * (float)b)) * 0.5f);
    while ((bi + 1) * (129 - (bi + 1)) / 2 <= b) ++bi;
    while (bi * (129 - bi) / 2 > b) --bi;
    const int bj = bi + (b - bi * (129 - bi) / 2);
    const int i0 = bi * 8, j0 = bj * 8;

    const int t = threadIdx.x;
    const int q  = t >> 6;                               // K-quarter = wave id
    const int qu = __builtin_amdgcn_readfirstlane(q);    // wave-uniform -> s_load bases
    const int l = t & 63;
    const int pi = l >> 3, pj = l & 7;
    const int i = i0 + pi, j = j0 + pj;

    __shared__ double smem_d[2176];                 // 17408 B
    double* sA  = smem_d;                           // [4*8][34]
    double* sB  = smem_d + 1088;
    float*  sSa = (float*)smem_d;                   // [4*8][68]
    float*  sSb = (float*)smem_d + 2176;
    double* lgbuf = smem_d;                         // [3][64][10]
    float*  stbuf = (float*)(smem_d + 1920);        // [3][64]

    // ---------------- strength (fp32), K=64 per quarter ----------------
    #pragma unroll
    for (int u = 0; u < 4; ++u) {
        int idx = u * 256 + t;
        int kq  = idx & 15;
        int row = (idx >> 4) & 7;
        int qq  = (idx >> 7) & 3;
        int arr = idx >> 9;
        const float* src = arr ? (sb_f + (j0 + row) * 256) : (sa_f + (i0 + row) * 256);
        float4 v = *(const float4*)(src + qq * 64 + kq * 4);
        float* dst = (arr ? sSb : sSa) + (qq * 8 + row) * 68 + kq * 4;
        *(float4*)dst = v;
    }
    __syncthreads();
    float accs = 0.f;
    {
        const float* sw2q = sw2 + qu * 64;
        const float* ra = sSa + (q * 8 + pi) * 68;
        const float* rb = sSb + (q * 8 + pj) * 68;
        #pragma unroll 16
        for (int kk = 0; kk < 64; ++kk) {
            float h = fmaxf(ra[kk] + rb[kk], 0.f);
            accs = fmaf(h, sw2q[kk], accs);
        }
    }

    // ---------------- classifier (fp64), K=128 per quarter ----------------
    double lg[10];
    #pragma unroll
    for (int c = 0; c < 10; ++c) lg[c] = 0.0;
    const double* wq = cw2d + qu * 1280;

    for (int c4 = 0; c4 < 4; ++c4) {
        __syncthreads();   // prior reads of sA/sB (or sSa/sSb) done
        #pragma unroll
        for (int u = 0; u < 4; ++u) {
            int idx = u * 256 + t;
            int kq  = idx & 15;
            int row = (idx >> 4) & 7;
            int qq  = (idx >> 7) & 3;
            int arr = idx >> 9;
            const double* src = arr ? (cb_d + (j0 + row) * 512) : (ca_d + (i0 + row) * 512);
            double2 v = *(const double2*)(src + qq * 128 + c4 * 32 + kq * 2);
            double* dst = (arr ? sB : sA) + (qq * 8 + row) * 34 + kq * 2;
            *(double2*)dst = v;
        }
        __syncthreads();
        const double* ra = sA + (q * 8 + pi) * 34;
        const double* rb = sB + (q * 8 + pj) * 34;
        const double* wc = wq + c4 * 320;
        #pragma unroll 8
        for (int kk = 0; kk < 32; ++kk) {
            double h = fmax(ra[kk] + rb[kk], 0.0);
            const double* w = wc + kk * 10;
            #pragma unroll
            for (int c = 0; c < 10; ++c) lg[c] = fma(h, w[c], lg[c]);
        }
    }

    // ---------------- combine via LDS ----------------
    __syncthreads();
    if (q > 0) {
        double* dst = lgbuf + ((q - 1) * 64 + l) * 10;
        #pragma unroll
        for (int c = 0; c < 10; ++c) dst[c] = lg[c];
        stbuf[(q - 1) * 64 + l] = accs;
    }
    __syncthreads();
    if (q == 0) {
        #pragma unroll
        for (int w = 0; w < 3; ++w) {
            const double* srcb = lgbuf + (w * 64 + l) * 10;
            #pragma unroll
            for (int c = 0; c < 10; ++c) lg[c] += srcb[c];
        }
        float st = accs + stbuf[l] + stbuf[64 + l] + stbuf[128 + l] + sb2[0];

        #pragma unroll
        for (int c = 0; c < 10; ++c) lg[c] += (double)cb2[c];
        double mx = lg[0]; int am2 = 0;
        #pragma unroll
        for (int c = 1; c < 10; ++c) {
            if (lg[c] > mx) { mx = lg[c]; am2 = c; }   // first-max == np.argmax
        }
        float tf[10]; float s = 0.f;
        #pragma unroll
        for (int c = 0; c < 10; ++c) { tf[c] = (float)(lg[c] - mx); s += __expf(tf[c]); }
        float ls = __logf(s);

        if (j > i) {
            const int p = i * 511 - (i * (i - 1)) / 2 + (j - i - 1);
            float* tp = out + TYPES_OFF + p * 10;
            #pragma unroll
            for (int c = 0; c < 10; ++c) tp[c] = tf[c] - ls;
            out[ARGMAX_OFF + p] = (float)am2;
            out[STRENGTH_OFF + p] = 1.0f / (1.0f + __expf(-st));
        }
    }
}

extern "C" void kernel_launch(void* const* d_in, const int* in_sizes, int n_in,
                              void* d_out, int out_size, void* d_ws, size_t ws_size,
                              hipStream_t stream) {
    const float* F   = (const float*)d_in[0];
    const float* cw1 = (const float*)d_in[1];
    const float* cb1 = (const float*)d_in[2];
    const float* cw2 = (const float*)d_in[3];
    const float* cb2 = (const float*)d_in[4];
    const float* sw1 = (const float*)d_in[5];
    const float* sb1 = (const float*)d_in[6];
    const float* sw2 = (const float*)d_in[7];
    const float* sb2 = (const float*)d_in[8];
    float* out = (float*)d_out;

    char* ws = (char*)d_ws;
    double* ca_d = (double*)(ws);
    double* cb_d = (double*)(ws + 2097152);
    float*  sa_f = (float*)(ws + 4194304);
    float*  sb_f = (float*)(ws + 4718592);
    double* cw2d = (double*)(ws + 5242880);

    hipLaunchKernelGGL(init_ws_kernel, dim3(1024), dim3(256), 0, stream,
                       cb1, sb1, cw2, ca_d, cb_d, sa_f, sb_f, cw2d);
    hipLaunchKernelGGL(proj_kernel, dim3(640), dim3(256), 0, stream,
                       F, cw1, sw1, ca_d, cb_d, sa_f, sb_f);
    hipLaunchKernelGGL(pair_kernel, dim3(2080), dim3(256), 0, stream,
                       ca_d, cb_d, sa_f, sb_f, cw2d, cb2, sw2, sb2, out);
}

// Round 6
// 153.137 us; speedup vs baseline: 2.1007x; 1.2070x over previous
//
#include <hip/hip_runtime.h>
#include <math.h>

// Problem constants
#define NN 512
#define DD 512
#define NPAIRS 130816            // 512*511/2
#define TYPES_OFF 0              // [P,10] floats
#define ARGMAX_OFF 1308160      // [P] floats
#define STRENGTH_OFF 1438976    // [P] floats

// ws layout (byte offsets) — K-split-2 partials, summed in pair staging:
//   ca0  double[512][512] @ 0         (bias cb1 folded; k 0..255 of F@cw1[:D])
//   ca1  double[512][512] @ 2097152   (k 256..511)
//   cb0  double[512][512] @ 4194304   (F@cw1[D:], k 0..255)
//   cbp1 double[512][512] @ 6291456   (k 256..511)
//   sa0  float [512][256] @ 8388608   (bias sb1 folded)
//   sa1  float [512][256] @ 8912896
//   sb0  float [512][256] @ 9437184
//   sbp1 float [512][256] @ 9961472
//   cw2d double[512][10]  @ 10485760
// total 10,526,720 bytes

__device__ __forceinline__ void fma64_step(
    const float4& a0, const float4& a1,
    const float4& b0, const float4& b1, const float4& b2, const float4& b3,
    double acc[2][4])
{
    const float av[2][4] = {{a0.x,a0.y,a0.z,a0.w},{a1.x,a1.y,a1.z,a1.w}};
    const float bv[4][4] = {{b0.x,b0.y,b0.z,b0.w},{b1.x,b1.y,b1.z,b1.w},
                            {b2.x,b2.y,b2.z,b2.w},{b3.x,b3.y,b3.z,b3.w}};
    #pragma unroll
    for (int kk = 0; kk < 4; ++kk) {
        double ad0 = (double)av[0][kk], ad1 = (double)av[1][kk];
        #pragma unroll
        for (int c = 0; c < 4; ++c) {
            double bd = (double)bv[kk][c];
            acc[0][c] = fma(ad0, bd, acc[0][c]);
            acc[1][c] = fma(ad1, bd, acc[1][c]);
        }
    }
}

__device__ __forceinline__ void fma32_step(
    const float4& a0, const float4& a1,
    const float4& b0, const float4& b1, const float4& b2, const float4& b3,
    float acc[2][4])
{
    const float av[2][4] = {{a0.x,a0.y,a0.z,a0.w},{a1.x,a1.y,a1.z,a1.w}};
    const float bv[4][4] = {{b0.x,b0.y,b0.z,b0.w},{b1.x,b1.y,b1.z,b1.w},
                            {b2.x,b2.y,b2.z,b2.w},{b3.x,b3.y,b3.z,b3.w}};
    #pragma unroll
    for (int kk = 0; kk < 4; ++kk) {
        #pragma unroll
        for (int c = 0; c < 4; ++c) {
            acc[0][c] = fmaf(av[0][kk], bv[kk][c], acc[0][c]);
            acc[1][c] = fmaf(av[1][kk], bv[kk][c], acc[1][c]);
        }
    }
}

// Barrier-free, LDS-free, atomic-free projection GEMM.
// Wave = 8m x 64n tile, thread = 2m x 4n, K-split 2 into partial buffers.
// wid [0,2048):    fp64 classifier (out 512x1024)
// wid [2048,3072): fp32 strength   (out 512x512)
// blocks >= 768:   cw2 -> fp64 convert
__global__ __launch_bounds__(256, 4) void proj_kernel(
    const float* __restrict__ F, const float* __restrict__ cw1,
    const float* __restrict__ sw1,
    const float* __restrict__ cb1, const float* __restrict__ sb1,
    const float* __restrict__ cw2,
    double* __restrict__ ca0, double* __restrict__ ca1,
    double* __restrict__ cb0, double* __restrict__ cbp1,
    float* __restrict__ sa0, float* __restrict__ sa1,
    float* __restrict__ sb0, float* __restrict__ sbp1,
    double* __restrict__ cw2d)
{
    const int t = threadIdx.x;
    if (blockIdx.x >= 768) {               // cw2 convert tail blocks
        int idx = (blockIdx.x - 768) * 256 + t;
        if (idx < 5120) cw2d[idx] = (double)cw2[idx];
        return;
    }
    const int wid  = blockIdx.x * 4 + (t >> 6);
    const int lane = t & 63;
    const int mg = lane >> 4;              // 0..3  (2-row group)
    const int nq = lane & 15;              // 0..15 (4-col group)

    if (wid < 2048) {
        // ---------------- fp64 classifier projection ----------------
        const int z  = wid & 1;            // K half
        const int r  = wid >> 1;           // 0..1023
        const int nt = r & 15;             // 64-col tile over 1024
        const int mt = r >> 4;             // 0..63
        const int m0 = mt * 8;
        const int n  = nt * 64;
        const float* W = (n < 512) ? cw1 : cw1 + 512 * 512;
        const int n0   = (n < 512) ? n : n - 512;
        double* outp   = (n < 512) ? (z ? ca1 : ca0) : (z ? cbp1 : cb0);
        const bool addbias = (z == 0) && (n < 512);

        const int row0 = m0 + mg * 2;
        const int col0 = n0 + nq * 4;
        const float* pa0 = F + row0 * 512 + z * 256;
        const float* pa1 = pa0 + 512;
        const float* pb  = W + (z * 256) * 512 + col0;

        double acc[2][4];
        #pragma unroll
        for (int rr = 0; rr < 2; ++rr)
            #pragma unroll
            for (int cc = 0; cc < 4; ++cc) acc[rr][cc] = 0.0;

        float4 a0 = *(const float4*)(pa0);
        float4 a1 = *(const float4*)(pa1);
        float4 b0 = *(const float4*)(pb);
        float4 b1 = *(const float4*)(pb + 512);
        float4 b2 = *(const float4*)(pb + 1024);
        float4 b3 = *(const float4*)(pb + 1536);
        for (int s = 0; s < 63; ++s) {     // 64 k4-steps, software-pipelined
            float4 na0 = *(const float4*)(pa0 + (s + 1) * 4);
            float4 na1 = *(const float4*)(pa1 + (s + 1) * 4);
            const float* nb = pb + (s + 1) * 2048;
            float4 nb0 = *(const float4*)(nb);
            float4 nb1 = *(const float4*)(nb + 512);
            float4 nb2 = *(const float4*)(nb + 1024);
            float4 nb3 = *(const float4*)(nb + 1536);
            fma64_step(a0, a1, b0, b1, b2, b3, acc);
            a0 = na0; a1 = na1; b0 = nb0; b1 = nb1; b2 = nb2; b3 = nb3;
        }
        fma64_step(a0, a1, b0, b1, b2, b3, acc);

        #pragma unroll
        for (int rr = 0; rr < 2; ++rr) {
            double v[4];
            #pragma unroll
            for (int cc = 0; cc < 4; ++cc) {
                v[cc] = acc[rr][cc];
                if (addbias) v[cc] += (double)cb1[col0 + cc];
            }
            double* dst = outp + (row0 + rr) * 512 + col0;
            *(double2*)(dst + 0) = make_double2(v[0], v[1]);
            *(double2*)(dst + 2) = make_double2(v[2], v[3]);
        }
    } else {
        // ---------------- fp32 strength projection ----------------
        const int w2 = wid - 2048;
        const int z  = w2 & 1;
        const int r  = w2 >> 1;            // 0..511
        const int nt = r & 7;              // 64-col tile over 512
        const int mt = r >> 3;             // 0..63
        const int m0 = mt * 8;
        const int n  = nt * 64;
        const float* W = (n < 256) ? sw1 : sw1 + 512 * 256;
        const int n0   = (n < 256) ? n : n - 256;
        float* outp    = (n < 256) ? (z ? sa1 : sa0) : (z ? sbp1 : sb0);
        const bool addbias = (z == 0) && (n < 256);

        const int row0 = m0 + mg * 2;
        const int col0 = n0 + nq * 4;
        const float* pa0 = F + row0 * 512 + z * 256;
        const float* pa1 = pa0 + 512;
        const float* pb  = W + (z * 256) * 256 + col0;

        float acc[2][4];
        #pragma unroll
        for (int rr = 0; rr < 2; ++rr)
            #pragma unroll
            for (int cc = 0; cc < 4; ++cc) acc[rr][cc] = 0.f;

        float4 a0 = *(const float4*)(pa0);
        float4 a1 = *(const float4*)(pa1);
        float4 b0 = *(const float4*)(pb);
        float4 b1 = *(const float4*)(pb + 256);
        float4 b2 = *(const float4*)(pb + 512);
        float4 b3 = *(const float4*)(pb + 768);
        for (int s = 0; s < 63; ++s) {
            float4 na0 = *(const float4*)(pa0 + (s + 1) * 4);
            float4 na1 = *(const float4*)(pa1 + (s + 1) * 4);
            const float* nb = pb + (s + 1) * 1024;
            float4 nb0 = *(const float4*)(nb);
            float4 nb1 = *(const float4*)(nb + 256);
            float4 nb2 = *(const float4*)(nb + 512);
            float4 nb3 = *(const float4*)(nb + 768);
            fma32_step(a0, a1, b0, b1, b2, b3, acc);
            a0 = na0; a1 = na1; b0 = nb0; b1 = nb1; b2 = nb2; b3 = nb3;
        }
        fma32_step(a0, a1, b0, b1, b2, b3, acc);

        #pragma unroll
        for (int rr = 0; rr < 2; ++rr) {
            float4 v = make_float4(acc[rr][0], acc[rr][1], acc[rr][2], acc[rr][3]);
            if (addbias) {
                v.x += sb1[col0 + 0]; v.y += sb1[col0 + 1];
                v.z += sb1[col0 + 2]; v.w += sb1[col0 + 3];
            }
            *(float4*)(outp + (row0 + rr) * 256 + col0) = v;
        }
    }
}

// Pair phase: block = 8x8 pair tile, 4 waves = 4 K-quarters, LDS combine.
// Grid: 2080 triangular tiles. Staging sums the two K-split partials.
// NOTE: inner loops MUST stay scalar-read + partial-unroll (R3 form). Full unroll
// or wider per-iter weight footprints -> VGPR explosion -> lg[] spills to
// scratch (R2: 175 MB, R4: 149 MB WRITE_SIZE). Weights JIT, 10 at a time.
__global__ __launch_bounds__(256, 4) void pair_kernel(
    const double* __restrict__ ca0, const double* __restrict__ ca1,
    const double* __restrict__ cb0, const double* __restrict__ cbp1,
    const float* __restrict__ sa0, const float* __restrict__ sa1,
    const float* __restrict__ sb0, const float* __restrict__ sbp1,
    const double* __restrict__ cw2d, const float* __restrict__ cb2,
    const float* __restrict__ sw2, const float* __restrict__ sb2,
    float* __restrict__ out)
{
    // triangular tile decode: S(bi) = bi*(129-bi)/2
    const int b = blockIdx.x;
    int bi = (int)floorf((129.0f - sqrtf(16641.0f - 8.0f * (float)b)) * 0.5f);
    while ((bi + 1) * (129 - (bi + 1)) / 2 <= b) ++bi;
    while (bi * (129 - bi) / 2 > b) --bi;
    const int bj = bi + (b - bi * (129 - bi) / 2);
    const int i0 = bi * 8, j0 = bj * 8;

    const int t = threadIdx.x;
    const int q  = t >> 6;                               // K-quarter = wave id
    const int qu = __builtin_amdgcn_readfirstlane(q);    // wave-uniform -> s_load bases
    const int l = t & 63;
    const int pi = l >> 3, pj = l & 7;
    const int i = i0 + pi, j = j0 + pj;

    __shared__ double smem_d[2176];                 // 17408 B
    double* sA  = smem_d;                           // [4*8][34]
    double* sB  = smem_d + 1088;
    float*  sSa = (float*)smem_d;                   // [4*8][68]
    float*  sSb = (float*)smem_d + 2176;
    double* lgbuf = smem_d;                         // [3][64][10]
    float*  stbuf = (float*)(smem_d + 1920);        // [3][64]

    // ---------------- strength (fp32), K=64 per quarter ----------------
    #pragma unroll
    for (int u = 0; u < 4; ++u) {
        int idx = u * 256 + t;
        int kq  = idx & 15;
        int row = (idx >> 4) & 7;
        int qq  = (idx >> 7) & 3;
        int arr = idx >> 9;
        int off = (arr ? (j0 + row) : (i0 + row)) * 256 + qq * 64 + kq * 4;
        const float* s0 = arr ? sb0 : sa0;
        const float* s1 = arr ? sbp1 : sa1;
        float4 v0 = *(const float4*)(s0 + off);
        float4 v1 = *(const float4*)(s1 + off);
        float4 v = make_float4(v0.x + v1.x, v0.y + v1.y, v0.z + v1.z, v0.w + v1.w);
        float* dst = (arr ? sSb : sSa) + (qq * 8 + row) * 68 + kq * 4;
        *(float4*)dst = v;
    }
    __syncthreads();
    float accs = 0.f;
    {
        const float* sw2q = sw2 + qu * 64;
        const float* ra = sSa + (q * 8 + pi) * 68;
        const float* rb = sSb + (q * 8 + pj) * 68;
        #pragma unroll 16
        for (int kk = 0; kk < 64; ++kk) {
            float h = fmaxf(ra[kk] + rb[kk], 0.f);
            accs = fmaf(h, sw2q[kk], accs);
        }
    }

    // ---------------- classifier (fp64), K=128 per quarter ----------------
    double lg[10];
    #pragma unroll
    for (int c = 0; c < 10; ++c) lg[c] = 0.0;
    const double* wq = cw2d + qu * 1280;

    for (int c4 = 0; c4 < 4; ++c4) {
        __syncthreads();   // prior reads of sA/sB (or sSa/sSb) done
        #pragma unroll
        for (int u = 0; u < 4; ++u) {
            int idx = u * 256 + t;
            int kq  = idx & 15;
            int row = (idx >> 4) & 7;
            int qq  = (idx >> 7) & 3;
            int arr = idx >> 9;
            int off = (arr ? (j0 + row) : (i0 + row)) * 512 + qq * 128 + c4 * 32 + kq * 2;
            const double* d0 = arr ? cb0 : ca0;
            const double* d1 = arr ? cbp1 : ca1;
            double2 u0 = *(const double2*)(d0 + off);
            double2 u1 = *(const double2*)(d1 + off);
            double2 v = make_double2(u0.x + u1.x, u0.y + u1.y);
            double* dst = (arr ? sB : sA) + (qq * 8 + row) * 34 + kq * 2;
            *(double2*)dst = v;
        }
        __syncthreads();
        const double* ra = sA + (q * 8 + pi) * 34;
        const double* rb = sB + (q * 8 + pj) * 34;
        const double* wc = wq + c4 * 320;
        #pragma unroll 8
        for (int kk = 0; kk < 32; ++kk) {
            double h = fmax(ra[kk] + rb[kk], 0.0);
            const double* w = wc + kk * 10;
            #pragma unroll
            for (int c = 0; c < 10; ++c) lg[c] = fma(h, w[c], lg[c]);
        }
    }

    // ---------------- combine via LDS ----------------
    __syncthreads();
    if (q > 0) {
        double* dst = lgbuf + ((q - 1) * 64 + l) * 10;
        #pragma unroll
        for (int c = 0; c < 10; ++c) dst[c] = lg[c];
        stbuf[(q - 1) * 64 + l] = accs;
    }
    __syncthreads();
    if (q == 0) {
        #pragma unroll
        for (int w = 0; w < 3; ++w) {
            const double* srcb = lgbuf + (w * 64 + l) * 10;
            #pragma unroll
            for (int c = 0; c < 10; ++c) lg[c] += srcb[c];
        }
        float st = accs + stbuf[l] + stbuf[64 + l] + stbuf[128 + l] + sb2[0];

        #pragma unroll
        for (int c = 0; c < 10; ++c) lg[c] += (double)cb2[c];
        double mx = lg[0]; int am2 = 0;
        #pragma unroll
        for (int c = 1; c < 10; ++c) {
            if (lg[c] > mx) { mx = lg[c]; am2 = c; }   // first-max == np.argmax
        }
        float tf[10]; float s = 0.f;
        #pragma unroll
        for (int c = 0; c < 10; ++c) { tf[c] = (float)(lg[c] - mx); s += __expf(tf[c]); }
        float ls = __logf(s);

        if (j > i) {
            const int p = i * 511 - (i * (i - 1)) / 2 + (j - i - 1);
            float* tp = out + TYPES_OFF + p * 10;
            #pragma unroll
            for (int c = 0; c < 10; ++c) tp[c] = tf[c] - ls;
            out[ARGMAX_OFF + p] = (float)am2;
            out[STRENGTH_OFF + p] = 1.0f / (1.0f + __expf(-st));
        }
    }
}

extern "C" void kernel_launch(void* const* d_in, const int* in_sizes, int n_in,
                              void* d_out, int out_size, void* d_ws, size_t ws_size,
                              hipStream_t stream) {
    const float* F   = (const float*)d_in[0];
    const float* cw1 = (const float*)d_in[1];
    const float* cb1 = (const float*)d_in[2];
    const float* cw2 = (const float*)d_in[3];
    const float* cb2 = (const float*)d_in[4];
    const float* sw1 = (const float*)d_in[5];
    const float* sb1 = (const float*)d_in[6];
    const float* sw2 = (const float*)d_in[7];
    const float* sb2 = (const float*)d_in[8];
    float* out = (float*)d_out;

    char* ws = (char*)d_ws;
    double* ca0  = (double*)(ws);
    double* ca1  = (double*)(ws + 2097152);
    double* cb0  = (double*)(ws + 4194304);
    double* cbp1 = (double*)(ws + 6291456);
    float*  sa0  = (float*)(ws + 8388608);
    float*  sa1  = (float*)(ws + 8912896);
    float*  sb0  = (float*)(ws + 9437184);
    float*  sbp1 = (float*)(ws + 9961472);
    double* cw2d = (double*)(ws + 10485760);

    hipLaunchKernelGGL(proj_kernel, dim3(788), dim3(256), 0, stream,
                       F, cw1, sw1, cb1, sb1, cw2,
                       ca0, ca1, cb0, cbp1, sa0, sa1, sb0, sbp1, cw2d);
    hipLaunchKernelGGL(pair_kernel, dim3(2080), dim3(256), 0, stream,
                       ca0, ca1, cb0, cbp1, sa0, sa1, sb0, sbp1,
                       cw2d, cb2, sw2, sb2, out);
}